// Round 3
// baseline (4613.722 us; speedup 1.0000x reference)
//
#include <hip/hip_runtime.h>
#include <math.h>

#define BB 32
#define HH 1024
#define TT 100
#define TH (TT * HH)
#define NSTEP 200

typedef _Float16 half8 __attribute__((ext_vector_type(8)));
typedef float f32x4 __attribute__((ext_vector_type(4)));

#define MFMA16 __builtin_amdgcn_mfma_f32_16x16x32_f16

// ---------------- bias sum ----------------
__global__ __launch_bounds__(256) void bias_sum_kernel(
    const float* bih0, const float* bhh0, const float* bih1, const float* bhh1,
    float* bsum0, float* bsum1)
{
    int i = blockIdx.x * blockDim.x + threadIdx.x;
    if (i < 4096)      bsum0[i] = bih0[i] + bhh0[i];
    else if (i < 8192) bsum1[i - 4096] = bih1[i - 4096] + bhh1[i - 4096];
}

// ---------------- x / targets -> fp16, transposed to [T][B][H] ----------------
__global__ __launch_bounds__(256) void cvt_pack_x(
    const float* __restrict__ X, const float* __restrict__ Tg,
    _Float16* __restrict__ X16, _Float16* __restrict__ Tg16)
{
    int id  = blockIdx.x * 256 + threadIdx.x;   // 0 .. 819199
    int tsr = id / 409600;
    int rem = id - tsr * 409600;
    int t   = rem >> 12;         // 0..99
    int rb  = rem & 4095;
    int b   = rb >> 7;
    int h8  = rb & 127;
    const float* s = tsr ? Tg : X;
    _Float16*    d = tsr ? Tg16 : X16;
    const float* sp = s + (size_t)b * TH + (size_t)t * HH + h8 * 8;
    float4 v0 = *(const float4*)sp;
    float4 v1 = *(const float4*)(sp + 4);
    half8 h;
    h[0] = (_Float16)v0.x; h[1] = (_Float16)v0.y; h[2] = (_Float16)v0.z; h[3] = (_Float16)v0.w;
    h[4] = (_Float16)v1.x; h[5] = (_Float16)v1.y; h[6] = (_Float16)v1.z; h[7] = (_Float16)v1.w;
    *(half8*)(d + ((size_t)t * BB + b) * HH + h8 * 8) = h;
}

// ---------------- weight packing (fp16, MFMA B-fragment stream order) --------
// Wp layout per layer: [hb 128][w 8][s 8][nt 2][lane 64][i 8]
//   nl = nt*16 + (lane&15); gate = nl>>3; col = hb*8 + (nl&7); n = gate*1024+col
//   k  = w*256 + s*32 + (lane>>4)*8 + i ; k<1024 -> Wih[n][k], else Whh[n][k-1024]
__global__ __launch_bounds__(256) void pack_w(
    const float* __restrict__ Wih0, const float* __restrict__ Whh0,
    const float* __restrict__ Wih1, const float* __restrict__ Whh1,
    _Float16* __restrict__ Wp0, _Float16* __restrict__ Wp1)
{
    int id    = blockIdx.x * 256 + threadIdx.x;   // 0 .. 2^21-1
    int lane  = id & 63;
    int nt    = (id >> 6) & 1;
    int s     = (id >> 7) & 7;
    int w     = (id >> 10) & 7;
    int hb    = (id >> 13) & 127;
    int layer = id >> 20;
    const float* Wih = layer ? Wih1 : Wih0;
    const float* Whh = layer ? Whh1 : Whh0;
    _Float16*    Wp  = layer ? Wp1 : Wp0;

    int nl   = nt * 16 + (lane & 15);
    int gate = nl >> 3;
    int col  = hb * 8 + (nl & 7);
    int n    = gate * HH + col;
    int k    = w * 256 + s * 32 + ((lane >> 4) & 3) * 8;
    const float* src = (k < 1024) ? (Wih + (size_t)n * HH + k)
                                  : (Whh + (size_t)n * HH + (k - 1024));
    float4 v0 = *(const float4*)src;
    float4 v1 = *(const float4*)(src + 4);
    half8 d;
    d[0] = (_Float16)v0.x; d[1] = (_Float16)v0.y; d[2] = (_Float16)v0.z; d[3] = (_Float16)v0.w;
    d[4] = (_Float16)v1.x; d[5] = (_Float16)v1.y; d[6] = (_Float16)v1.z; d[7] = (_Float16)v1.w;
    *(half8*)(Wp + (size_t)(id & 0xFFFFF) * 8) = d;
}

// ---------------- persistent pipelined LSTM ----------------
struct PArgs {
    const _Float16* X16;    // [T][B][H]
    const _Float16* Tg16;   // [T][B][H]
    const _Float16* Wp0;
    const _Float16* Wp1;
    const float* bsum0;
    const float* bsum1;
    _Float16* h0r;          // [4][B][H] ring
    _Float16* h1r;          // [4][B][H] ring
    int* ctr0;
    int* ctr1;
    float* out;             // [B][T][H]
};

// grid 256 x 512. WGs 0..127: layer0 ("role0"), 128..255: layer1 ("role1").
// Each WG: 8 hidden cols x 4 gates x 32 batches; weights resident in VGPRs.
__global__ __launch_bounds__(512, 2) void lstm_persist(PArgs A)
{
    __shared__ float part[8][32][33];     // 33.8 KB
    __shared__ float ldspad[12800];       // +50 KB -> forces 1 WG/CU

    const int wg   = blockIdx.x;
    const int role = wg >> 7;
    const int hb   = wg & 127;
    const int tid  = threadIdx.x;
    const int w    = tid >> 6;
    const int lane = tid & 63;
    const int lr   = lane & 15;
    const int lg   = lane >> 4;
    const bool isx = (w < 4);
    const int koff = (w & 3) * 256 + lg * 8;

    if (A.out == (float*)1) {             // never true; keeps ldspad allocated
        ldspad[tid] = (float)tid;
        part[0][0][0] = ldspad[511 - tid];
    }

    const _Float16* Wp = role ? A.Wp1 : A.Wp0;
    const float* bsum  = role ? A.bsum1 : A.bsum0;
    _Float16* hself    = role ? A.h1r : A.h0r;
    int* ctr_self      = role ? A.ctr1 : A.ctr0;
    int* ctr_other     = role ? A.ctr0 : A.ctr1;

    // ---- one-time: weight slice -> registers (64 VGPRs/lane) ----
    half8 wreg[16];
    {
        const half8* wp = (const half8*)Wp + (size_t)(hb * 8 + w) * 1024 + lane;
#pragma unroll
        for (int sn = 0; sn < 16; ++sn) wreg[sn] = wp[(size_t)sn * 64];
    }

    // epilogue-thread persistent state: bias regs + fp32 cell register
    const int eb = tid >> 3, ec = tid & 7, ecol = hb * 8 + ec;
    float breg[4], creg = 0.f;
    if (tid < 256) {
#pragma unroll
        for (int g = 0; g < 4; ++g) breg[g] = bsum[g * HH + ecol];
    }

    bool dead = false;

    for (int p = 0; p < NSTEP; ++p) {
        // ---------- waits ----------
        int tgt_self, tgt_oth;
        if (role == 0) {
            tgt_self = 128 * p;                          // h0[p-1] complete
            tgt_oth  = (p >= 4) ? 128 * (p - 3) : 0;     // ring-4 WAR vs role1
            if (p == 100) tgt_oth = 128 * 100;           // needs h1[99] (="last")
        } else {
            tgt_self = 128 * p;                          // h1[p-1]
            tgt_oth  = 128 * (p + 1);                    // h0[p]
        }
        if (tid == 0 && !dead) {
            unsigned spins = 0;
            while (__hip_atomic_load(ctr_self, __ATOMIC_RELAXED, __HIP_MEMORY_SCOPE_AGENT) < tgt_self) {
                __builtin_amdgcn_s_sleep(1);
                if (++spins > (1u << 22)) { dead = true; break; }
            }
            while (!dead &&
                   __hip_atomic_load(ctr_other, __ATOMIC_RELAXED, __HIP_MEMORY_SCOPE_AGENT) < tgt_oth) {
                __builtin_amdgcn_s_sleep(1);
                if (++spins > (1u << 22)) { dead = true; break; }
            }
            __threadfence();   // acquire: invalidate L1/L2 so h reads are fresh
        }
        __syncthreads();

        // ---------- A-operand base (wave-uniform) ----------
        const _Float16* abase;
        if (isx) {
            if (role) {
                abase = A.h0r + (size_t)(p & 3) * (BB * HH);          // h0[p]
            } else if (p < 100) {
                abase = A.X16 + (size_t)p * (BB * HH);                // encoder x_t
            } else if (p == 100) {
                abase = A.h1r + (size_t)3 * (BB * HH);                // h1[99] = "last"
            } else {
                abase = A.Tg16 + (size_t)(p - 100) * (BB * HH);       // teacher forcing
            }
        } else {
            abase = hself + (size_t)((p - 1) & 3) * (BB * HH);        // own h[t-1]
        }
        const _Float16* aptr = abase + koff + lr * HH;

        // ---------- MFMA: 32 per wave, K-slice from registers ----------
        f32x4 acc[2][2] = {};
#pragma unroll
        for (int s = 0; s < 8; ++s) {
            half8 a0 = *(const half8*)(aptr + s * 32);
            half8 a1 = *(const half8*)(aptr + 16 * HH + s * 32);
            acc[0][0] = MFMA16(a0, wreg[2 * s],     acc[0][0], 0, 0, 0);
            acc[0][1] = MFMA16(a0, wreg[2 * s + 1], acc[0][1], 0, 0, 0);
            acc[1][0] = MFMA16(a1, wreg[2 * s],     acc[1][0], 0, 0, 0);
            acc[1][1] = MFMA16(a1, wreg[2 * s + 1], acc[1][1], 0, 0, 0);
        }

        // ---------- cross-wave reduction ----------
#pragma unroll
        for (int mt = 0; mt < 2; ++mt)
#pragma unroll
            for (int nt = 0; nt < 2; ++nt)
#pragma unroll
                for (int j = 0; j < 4; ++j)
                    part[w][16 * mt + lg * 4 + j][16 * nt + lr] = acc[mt][nt][j];
        __syncthreads();

        // ---------- fused cell epilogue ----------
        if (tid < 256) {
            float g4[4];
#pragma unroll
            for (int g = 0; g < 4; ++g) {
                float s0 = 0.f;
#pragma unroll
                for (int pw = 0; pw < 8; ++pw) s0 += part[pw][eb][g * 8 + ec];
                g4[g] = s0 + breg[g];
            }
            float ig = 1.f / (1.f + __expf(-g4[0]));
            float fg = 1.f / (1.f + __expf(-g4[1]));
            float gg = 2.f / (1.f + __expf(-2.f * g4[2])) - 1.f;
            float og = 1.f / (1.f + __expf(-g4[3]));
            float cn = fg * creg + ig * gg;
            float tc = 2.f / (1.f + __expf(-2.f * cn)) - 1.f;
            float hn = og * tc;
            creg = cn;
            hself[(size_t)(p & 3) * (BB * HH) + (size_t)eb * HH + ecol] = (_Float16)hn;
            if (role && p >= 100)
                A.out[(size_t)eb * TH + (size_t)(p - 100) * HH + ecol] = hn;
        }
        __syncthreads();

        // ---------- signal ----------
        if (tid == 0) {
            __threadfence();   // release: write back dirty L2 before signaling
            __hip_atomic_fetch_add(ctr_self, 1, __ATOMIC_RELEASE, __HIP_MEMORY_SCOPE_AGENT);
        }
    }
}

extern "C" void kernel_launch(void* const* d_in, const int* in_sizes, int n_in,
                              void* d_out, int out_size, void* d_ws, size_t ws_size,
                              hipStream_t stream)
{
    const float* X    = (const float*)d_in[0];
    const float* Tg   = (const float*)d_in[1];
    const float* Wih0 = (const float*)d_in[2];
    const float* Whh0 = (const float*)d_in[3];
    const float* bih0 = (const float*)d_in[4];
    const float* bhh0 = (const float*)d_in[5];
    const float* Wih1 = (const float*)d_in[6];
    const float* Whh1 = (const float*)d_in[7];
    const float* bih1 = (const float*)d_in[8];
    const float* bhh1 = (const float*)d_in[9];
    float* out = (float*)d_out;

    char* p = (char*)d_ws;
    _Float16* h0r = (_Float16*)p; p += 4 * BB * HH * 2;     // 256 KB
    _Float16* h1r = (_Float16*)p; p += 4 * BB * HH * 2;     // 256 KB
    int* ctr0 = (int*)p;
    int* ctr1 = (int*)(p + 128);  p += 256;
    const size_t zbytes = (size_t)(p - (char*)d_ws);
    float* bsum0 = (float*)p; p += 4096 * sizeof(float);
    float* bsum1 = (float*)p; p += 4096 * sizeof(float);
    _Float16* X16  = (_Float16*)p; p += (size_t)TT * BB * HH * 2;
    _Float16* Tg16 = (_Float16*)p; p += (size_t)TT * BB * HH * 2;
    _Float16* Wp0  = (_Float16*)p; p += (size_t)4096 * 2048 * 2;
    _Float16* Wp1  = (_Float16*)p;

    hipMemsetAsync(d_ws, 0, zbytes, stream);
    bias_sum_kernel<<<32, 256, 0, stream>>>(bih0, bhh0, bih1, bhh1, bsum0, bsum1);
    cvt_pack_x<<<3200, 256, 0, stream>>>(X, Tg, X16, Tg16);
    pack_w<<<8192, 256, 0, stream>>>(Wih0, Whh0, Wih1, Whh1, Wp0, Wp1);

    PArgs A;
    A.X16 = X16; A.Tg16 = Tg16; A.Wp0 = Wp0; A.Wp1 = Wp1;
    A.bsum0 = bsum0; A.bsum1 = bsum1;
    A.h0r = h0r; A.h1r = h1r; A.ctr0 = ctr0; A.ctr1 = ctr1;
    A.out = out;
    lstm_persist<<<256, 512, 0, stream>>>(A);
}

// Round 4
// 1593.019 us; speedup vs baseline: 2.8962x; 2.8962x over previous
//
#include <hip/hip_runtime.h>
#include <math.h>

#define BB 32
#define HH 1024
#define TT 100
#define TH (TT * HH)
#define NSTEP 200

typedef _Float16 half8 __attribute__((ext_vector_type(8)));
typedef float f32x4 __attribute__((ext_vector_type(4)));

#define MFMA16 __builtin_amdgcn_mfma_f32_16x16x32_f16

// ---------------- coherent (LLC-level) access helpers ----------------
__device__ __forceinline__ void llc_load8(const _Float16* p, half8& v) {
    asm volatile("global_load_dwordx4 %0, %1, off sc0 sc1" : "=v"(v) : "v"(p));
}
__device__ __forceinline__ void st_sc_u16(_Float16* p, unsigned v) {
    asm volatile("global_store_short %0, %1, off sc0 sc1" :: "v"(p), "v"(v) : "memory");
}
__device__ __forceinline__ void st_sc_f32(float* p, float v) {
    asm volatile("global_store_dword %0, %1, off sc0 sc1" :: "v"(p), "v"(v) : "memory");
}
__device__ __forceinline__ int llc_poll(const int* p) {
    int v;
    asm volatile("global_load_dword %0, %1, off sc0 sc1\n\ts_waitcnt vmcnt(0)"
                 : "=v"(v) : "v"(p) : "memory");
    return v;
}
__device__ __forceinline__ void llc_bump(int* p) {
    int one = 1;
    asm volatile("s_waitcnt vmcnt(0)\n\tglobal_atomic_add %0, %1, off sc1"
                 :: "v"(p), "v"(one) : "memory");
}

// ---------------- bias sum ----------------
__global__ __launch_bounds__(256) void bias_sum_kernel(
    const float* bih0, const float* bhh0, const float* bih1, const float* bhh1,
    float* bsum0, float* bsum1)
{
    int i = blockIdx.x * blockDim.x + threadIdx.x;
    if (i < 4096)      bsum0[i] = bih0[i] + bhh0[i];
    else if (i < 8192) bsum1[i - 4096] = bih1[i - 4096] + bhh1[i - 4096];
}

// ---------------- x / targets -> fp16, transposed to [T][B][H] ----------------
__global__ __launch_bounds__(256) void cvt_pack_x(
    const float* __restrict__ X, const float* __restrict__ Tg,
    _Float16* __restrict__ X16, _Float16* __restrict__ Tg16)
{
    int id  = blockIdx.x * 256 + threadIdx.x;   // 0 .. 819199
    int tsr = id / 409600;
    int rem = id - tsr * 409600;
    int t   = rem >> 12;
    int rb  = rem & 4095;
    int b   = rb >> 7;
    int h8  = rb & 127;
    const float* s = tsr ? Tg : X;
    _Float16*    d = tsr ? Tg16 : X16;
    const float* sp = s + (size_t)b * TH + (size_t)t * HH + h8 * 8;
    float4 v0 = *(const float4*)sp;
    float4 v1 = *(const float4*)(sp + 4);
    half8 h;
    h[0] = (_Float16)v0.x; h[1] = (_Float16)v0.y; h[2] = (_Float16)v0.z; h[3] = (_Float16)v0.w;
    h[4] = (_Float16)v1.x; h[5] = (_Float16)v1.y; h[6] = (_Float16)v1.z; h[7] = (_Float16)v1.w;
    *(half8*)(d + ((size_t)t * BB + b) * HH + h8 * 8) = h;
}

// ---------------- weight packing (fp16, MFMA B-fragment stream order) --------
__global__ __launch_bounds__(256) void pack_w(
    const float* __restrict__ Wih0, const float* __restrict__ Whh0,
    const float* __restrict__ Wih1, const float* __restrict__ Whh1,
    _Float16* __restrict__ Wp0, _Float16* __restrict__ Wp1)
{
    int id    = blockIdx.x * 256 + threadIdx.x;   // 0 .. 2^21-1
    int lane  = id & 63;
    int nt    = (id >> 6) & 1;
    int s     = (id >> 7) & 7;
    int w     = (id >> 10) & 7;
    int hb    = (id >> 13) & 127;
    int layer = id >> 20;
    const float* Wih = layer ? Wih1 : Wih0;
    const float* Whh = layer ? Whh1 : Whh0;
    _Float16*    Wp  = layer ? Wp1 : Wp0;

    int nl   = nt * 16 + (lane & 15);
    int gate = nl >> 3;
    int col  = hb * 8 + (nl & 7);
    int n    = gate * HH + col;
    int k    = w * 256 + s * 32 + ((lane >> 4) & 3) * 8;
    const float* src = (k < 1024) ? (Wih + (size_t)n * HH + k)
                                  : (Whh + (size_t)n * HH + (k - 1024));
    float4 v0 = *(const float4*)src;
    float4 v1 = *(const float4*)(src + 4);
    half8 d;
    d[0] = (_Float16)v0.x; d[1] = (_Float16)v0.y; d[2] = (_Float16)v0.z; d[3] = (_Float16)v0.w;
    d[4] = (_Float16)v1.x; d[5] = (_Float16)v1.y; d[6] = (_Float16)v1.z; d[7] = (_Float16)v1.w;
    *(half8*)(Wp + (size_t)(id & 0xFFFFF) * 8) = d;
}

// ---------------- persistent pipelined LSTM ----------------
struct PArgs {
    const _Float16* X16;    // [T][B][H]
    const _Float16* Tg16;   // [T][B][H]
    const _Float16* Wp0;
    const _Float16* Wp1;
    const float* bsum0;
    const float* bsum1;
    _Float16* h0r;          // [4][B][H] ring
    _Float16* h1r;          // [4][B][H] ring
    int* ctr0;
    int* ctr1;
    float* out;             // [B][T][H]
};

__global__ __launch_bounds__(512, 2) void lstm_persist(PArgs A)
{
    __shared__ float part[8][32][34];     // 34.8 KB (stride 34: free 2-way banks)
    __shared__ float ldspad[11776];       // pad -> 81.9 KB total -> 1 WG/CU

    const int wg   = blockIdx.x;
    const int role = wg >> 7;
    const int hb   = wg & 127;
    const int tid  = threadIdx.x;
    const int w    = tid >> 6;
    const int lane = tid & 63;
    const int lr   = lane & 15;
    const int lg   = lane >> 4;
    const bool isx = (w < 4);
    const int koff = (w & 3) * 256 + lg * 8;

    if (A.out == (float*)1) {             // never true; keeps ldspad allocated
        ldspad[tid] = (float)tid;
        part[0][0][0] = ldspad[511 - tid];
    }

    const _Float16* Wp = role ? A.Wp1 : A.Wp0;
    const float* bsum  = role ? A.bsum1 : A.bsum0;
    _Float16* hself    = role ? A.h1r : A.h0r;
    int* ctr_self      = role ? A.ctr1 : A.ctr0;
    int* ctr_other     = role ? A.ctr0 : A.ctr1;

    // ---- one-time: weight slice -> registers (64 VGPRs/lane) ----
    half8 wreg[16];
    {
        const half8* wp = (const half8*)Wp + (size_t)(hb * 8 + w) * 1024 + lane;
#pragma unroll
        for (int sn = 0; sn < 16; ++sn) wreg[sn] = wp[(size_t)sn * 64];
    }

    const int eb = tid >> 3, ec = tid & 7, ecol = hb * 8 + ec;
    float breg[4], creg = 0.f;
    if (tid < 256) {
#pragma unroll
        for (int g = 0; g < 4; ++g) breg[g] = bsum[g * HH + ecol];
    }

    bool dead = false;

    for (int p = 0; p < NSTEP; ++p) {
        // ---------- waits (tid 0 polls LLC counters; no cache-wide fences) ----
        int tgt_self, tgt_oth;
        if (role == 0) {
            tgt_self = 128 * p;
            tgt_oth  = (p >= 4) ? 128 * (p - 3) : 0;     // ring-4 WAR vs role1
            if (p == 100) tgt_oth = 128 * 100;           // needs h1[99] ("last")
        } else {
            tgt_self = 128 * p;                          // own h1[p-1]
            tgt_oth  = 128 * (p + 1);                    // h0[p]
        }
        if (tid == 0 && !dead) {
            unsigned spins = 0;
            while (llc_poll(ctr_self) < tgt_self) {
                __builtin_amdgcn_s_sleep(1);
                if (++spins > (1u << 20)) { dead = true; break; }
            }
            while (!dead && llc_poll(ctr_other) < tgt_oth) {
                __builtin_amdgcn_s_sleep(1);
                if (++spins > (1u << 20)) { dead = true; break; }
            }
        }
        __syncthreads();

        // ---------- A-operand base (wave-uniform) ----------
        const _Float16* abase;
        bool coh;                       // operand produced during this kernel?
        if (isx) {
            if (role) {
                abase = A.h0r + (size_t)(p & 3) * (BB * HH);          coh = true;
            } else if (p < 100) {
                abase = A.X16 + (size_t)p * (BB * HH);                coh = false;
            } else if (p == 100) {
                abase = A.h1r + (size_t)3 * (BB * HH);                coh = true;
            } else {
                abase = A.Tg16 + (size_t)(p - 100) * (BB * HH);       coh = false;
            }
        } else {
            abase = hself + (size_t)((p - 1) & 3) * (BB * HH);        coh = true;
        }
        const _Float16* aptr = abase + koff + (size_t)lr * HH;

        // ---------- A fragments ----------
        half8 a[16];
        if (coh) {
#pragma unroll
            for (int s = 0; s < 8; ++s) {
                llc_load8(aptr + s * 32, a[2 * s]);
                llc_load8(aptr + 16 * HH + s * 32, a[2 * s + 1]);
            }
            asm volatile("s_waitcnt vmcnt(0)"
                : "+v"(a[0]), "+v"(a[1]), "+v"(a[2]),  "+v"(a[3]),
                  "+v"(a[4]), "+v"(a[5]), "+v"(a[6]),  "+v"(a[7]),
                  "+v"(a[8]), "+v"(a[9]), "+v"(a[10]), "+v"(a[11]),
                  "+v"(a[12]),"+v"(a[13]),"+v"(a[14]), "+v"(a[15])
                :: "memory");
            __builtin_amdgcn_sched_barrier(0);
        } else {
#pragma unroll
            for (int s = 0; s < 8; ++s) {
                a[2 * s]     = *(const half8*)(aptr + s * 32);
                a[2 * s + 1] = *(const half8*)(aptr + 16 * HH + s * 32);
            }
        }

        // ---------- MFMA: 32 per wave, weights from registers ----------
        f32x4 acc[2][2] = {};
#pragma unroll
        for (int s = 0; s < 8; ++s) {
            acc[0][0] = MFMA16(a[2 * s],     wreg[2 * s],     acc[0][0], 0, 0, 0);
            acc[0][1] = MFMA16(a[2 * s],     wreg[2 * s + 1], acc[0][1], 0, 0, 0);
            acc[1][0] = MFMA16(a[2 * s + 1], wreg[2 * s],     acc[1][0], 0, 0, 0);
            acc[1][1] = MFMA16(a[2 * s + 1], wreg[2 * s + 1], acc[1][1], 0, 0, 0);
        }

        // ---------- cross-wave reduction ----------
#pragma unroll
        for (int mt = 0; mt < 2; ++mt)
#pragma unroll
            for (int nt = 0; nt < 2; ++nt)
#pragma unroll
                for (int j = 0; j < 4; ++j)
                    part[w][16 * mt + lg * 4 + j][16 * nt + lr] = acc[mt][nt][j];
        __syncthreads();

        // ---------- fused cell epilogue ----------
        if (tid < 256) {
            float g4[4];
#pragma unroll
            for (int g = 0; g < 4; ++g) {
                float s0 = 0.f;
#pragma unroll
                for (int pw = 0; pw < 8; ++pw) s0 += part[pw][eb][g * 8 + ec];
                g4[g] = s0 + breg[g];
            }
            float ig = 1.f / (1.f + __expf(-g4[0]));
            float fg = 1.f / (1.f + __expf(-g4[1]));
            float gg = 2.f / (1.f + __expf(-2.f * g4[2])) - 1.f;
            float og = 1.f / (1.f + __expf(-g4[3]));
            float cn = fg * creg + ig * gg;
            float tc = 2.f / (1.f + __expf(-2.f * cn)) - 1.f;
            float hn = og * tc;
            creg = cn;
            unsigned hb16 = (unsigned)__builtin_bit_cast(unsigned short, (_Float16)hn);
            st_sc_u16(hself + (size_t)(p & 3) * (BB * HH) + (size_t)eb * HH + ecol, hb16);
            if (role && p >= 100)
                st_sc_f32(A.out + (size_t)eb * TH + (size_t)(p - 100) * HH + ecol, hn);
        }
        __syncthreads();   // per-wave vmcnt drain -> all h stores LLC-visible

        // ---------- signal ----------
        if (tid == 0) llc_bump(ctr_self);
    }
}

extern "C" void kernel_launch(void* const* d_in, const int* in_sizes, int n_in,
                              void* d_out, int out_size, void* d_ws, size_t ws_size,
                              hipStream_t stream)
{
    const float* X    = (const float*)d_in[0];
    const float* Tg   = (const float*)d_in[1];
    const float* Wih0 = (const float*)d_in[2];
    const float* Whh0 = (const float*)d_in[3];
    const float* bih0 = (const float*)d_in[4];
    const float* bhh0 = (const float*)d_in[5];
    const float* Wih1 = (const float*)d_in[6];
    const float* Whh1 = (const float*)d_in[7];
    const float* bih1 = (const float*)d_in[8];
    const float* bhh1 = (const float*)d_in[9];
    float* out = (float*)d_out;

    char* p = (char*)d_ws;
    _Float16* h0r = (_Float16*)p; p += 4 * BB * HH * 2;     // 256 KB
    _Float16* h1r = (_Float16*)p; p += 4 * BB * HH * 2;     // 256 KB
    int* ctr0 = (int*)p;
    int* ctr1 = (int*)(p + 128);  p += 256;
    const size_t zbytes = (size_t)(p - (char*)d_ws);
    float* bsum0 = (float*)p; p += 4096 * sizeof(float);
    float* bsum1 = (float*)p; p += 4096 * sizeof(float);
    _Float16* X16  = (_Float16*)p; p += (size_t)TT * BB * HH * 2;
    _Float16* Tg16 = (_Float16*)p; p += (size_t)TT * BB * HH * 2;
    _Float16* Wp0  = (_Float16*)p; p += (size_t)4096 * 2048 * 2;
    _Float16* Wp1  = (_Float16*)p;

    hipMemsetAsync(d_ws, 0, zbytes, stream);
    bias_sum_kernel<<<32, 256, 0, stream>>>(bih0, bhh0, bih1, bhh1, bsum0, bsum1);
    cvt_pack_x<<<3200, 256, 0, stream>>>(X, Tg, X16, Tg16);
    pack_w<<<8192, 256, 0, stream>>>(Wih0, Whh0, Wih1, Whh1, Wp0, Wp1);

    PArgs A;
    A.X16 = X16; A.Tg16 = Tg16; A.Wp0 = Wp0; A.Wp1 = Wp1;
    A.bsum0 = bsum0; A.bsum1 = bsum1;
    A.h0r = h0r; A.h1r = h1r; A.ctr0 = ctr0; A.ctr1 = ctr1;
    A.out = out;
    lstm_persist<<<256, 512, 0, stream>>>(A);
}